// Round 2
// baseline (118.108 us; speedup 1.0000x reference)
//
#include <hip/hip_runtime.h>
#include <hip/hip_bf16.h>

// RetinaNet matcher: gt_boxes [B=8, G=64, 4] f32, anchors [A=120000, 4] f32.
// Outputs (concatenated in d_out, f32): matched_idxs [B,A] (as float), matched_vals [B,A].
//
// Numerics: replicate np-f32 bit-exactly. *_rn intrinsics prevent
// -ffp-contract=fast from fusing add/mul into FMA (would break the
// `quality == highest_per_gt` exact-equality recovery step). argmax
// tie-break = first (lowest g), matching np.argmax. IoU >= 0, so the
// per-gt max reduces bit-exactly via atomicMax on the uint bit pattern.

static constexpr int G = 64;

__device__ __forceinline__ float iou_f(float gx1, float gy1, float gx2, float gy2,
                                       float garea,
                                       float ax1, float ay1, float ax2, float ay2,
                                       float aarea) {
    float ltx = fmaxf(gx1, ax1);
    float lty = fmaxf(gy1, ay1);
    float rbx = fminf(gx2, ax2);
    float rby = fminf(gy2, ay2);
    float w = fmaxf(__fsub_rn(rbx, ltx), 0.0f);
    float h = fmaxf(__fsub_rn(rby, lty), 0.0f);
    float inter = __fmul_rn(w, h);
    float denom = __fsub_rn(__fadd_rn(garea, aarea), inter);
    return __fdiv_rn(inter, denom);
}

__global__ void init_hpg(unsigned int* hpg, int n) {
    int i = blockIdx.x * blockDim.x + threadIdx.x;
    if (i < n) hpg[i] = 0u;  // 0u == 0.0f bits; IoU >= 0
}

// Pass 1: highest_per_gt[b*G+g] = max over anchors of IoU (bit-exact max via uint atomicMax).
// Block: 256 threads, 1024 anchors (4 per thread). Grid: (ceil(A/1024), B).
__global__ void pass1_hpg(const float* __restrict__ gt,
                          const float* __restrict__ anchors,
                          unsigned int* __restrict__ hpg, int A) {
    const int b = blockIdx.y;
    const int t = threadIdx.x;
    __shared__ float4 sgt[G];
    __shared__ float sga[G];
    __shared__ unsigned int sred[G];
    if (t < G) {
        const float4 gb = ((const float4*)gt)[b * G + t];
        sgt[t] = gb;
        sga[t] = __fmul_rn(__fsub_rn(gb.z, gb.x), __fsub_rn(gb.w, gb.y));
        sred[t] = 0u;
    }
    __syncthreads();

    const int base = blockIdx.x * 1024;
    float ax1[4], ay1[4], ax2[4], ay2[4], aar[4];
    bool val[4];
#pragma unroll
    for (int k = 0; k < 4; ++k) {
        int a = base + k * 256 + t;
        val[k] = (a < A);
        int aa = val[k] ? a : 0;
        const float4 ab = ((const float4*)anchors)[aa];
        ax1[k] = ab.x; ay1[k] = ab.y; ax2[k] = ab.z; ay2[k] = ab.w;
        aar[k] = __fmul_rn(__fsub_rn(ax2[k], ax1[k]), __fsub_rn(ay2[k], ay1[k]));
    }

    for (int g = 0; g < G; ++g) {
        float4 gb = sgt[g];
        float ga = sga[g];
        float m = 0.0f;
#pragma unroll
        for (int k = 0; k < 4; ++k) {
            float iou = iou_f(gb.x, gb.y, gb.z, gb.w, ga,
                              ax1[k], ay1[k], ax2[k], ay2[k], aar[k]);
            if (val[k]) m = fmaxf(m, iou);
        }
#pragma unroll
        for (int off = 32; off > 0; off >>= 1)
            m = fmaxf(m, __shfl_xor(m, off, 64));
        if ((t & 63) == 0) atomicMax(&sred[g], __float_as_uint(m));
    }
    __syncthreads();
    if (t < G) atomicMax(&hpg[b * G + t], sred[t]);
}

// Pass 2: per anchor -> max/argmax over g, thresholds, low-quality recovery, write f32.
// Block: 256 threads = 256 anchors. Grid: (ceil(A/256), B).
__global__ void pass2_match(const float* __restrict__ gt,
                            const float* __restrict__ anchors,
                            const unsigned int* __restrict__ hpg,
                            float* __restrict__ out_idx,
                            float* __restrict__ out_val, int A) {
    const int b = blockIdx.y;
    const int t = threadIdx.x;
    __shared__ float4 sgt[G];
    __shared__ float sga[G];
    __shared__ float shpg[G];
    if (t < G) {
        const float4 gb = ((const float4*)gt)[b * G + t];
        sgt[t] = gb;
        sga[t] = __fmul_rn(__fsub_rn(gb.z, gb.x), __fsub_rn(gb.w, gb.y));
        shpg[t] = __uint_as_float(hpg[b * G + t]);
    }
    __syncthreads();

    int a = blockIdx.x * 256 + t;
    if (a >= A) return;
    const float4 ab = ((const float4*)anchors)[a];
    float ax1 = ab.x, ay1 = ab.y, ax2 = ab.z, ay2 = ab.w;
    float aar = __fmul_rn(__fsub_rn(ax2, ax1), __fsub_rn(ay2, ay1));

    float vmax = -1.0f;
    int amax = 0;
    bool pu = false;
    for (int g = 0; g < G; ++g) {
        float4 gb = sgt[g];
        float iou = iou_f(gb.x, gb.y, gb.z, gb.w, sga[g], ax1, ay1, ax2, ay2, aar);
        if (iou > vmax) { vmax = iou; amax = g; }  // first-max tie-break (np.argmax)
        pu = pu || (iou == shpg[g]);
    }
    int m;
    if (pu) {
        m = amax;                       // low-quality match recovery
    } else if (vmax < 0.4f) {
        m = -1;                         // BELOW_LOW_QUALITY
    } else if (vmax < 0.5f) {
        m = -2;                         // BETWEEN_THRESHOLDS
    } else {
        m = amax;
    }
    size_t o = (size_t)b * A + a;
    out_idx[o] = (float)m;
    out_val[o] = vmax;
}

extern "C" void kernel_launch(void* const* d_in, const int* in_sizes, int n_in,
                              void* d_out, int out_size, void* d_ws, size_t ws_size,
                              hipStream_t stream) {
    const float* gt = (const float*)d_in[0];
    const float* anchors = (const float*)d_in[1];
    const int BG = in_sizes[0] / 4;   // B*G = 512
    const int B = BG / G;             // 8
    const int A = in_sizes[1] / 4;    // 120000

    unsigned int* hpg = (unsigned int*)d_ws;  // B*G uints = 2 KB
    float* out_idx = (float*)d_out;
    float* out_val = out_idx + (size_t)B * A;

    init_hpg<<<(BG + 255) / 256, 256, 0, stream>>>(hpg, BG);

    dim3 g1((A + 1023) / 1024, B);
    pass1_hpg<<<g1, 256, 0, stream>>>(gt, anchors, hpg, A);

    dim3 g2((A + 255) / 256, B);
    pass2_match<<<g2, 256, 0, stream>>>(gt, anchors, hpg, out_idx, out_val, A);
}